// Round 1
// baseline (225.193 us; speedup 1.0000x reference)
//
#include <hip/hip_runtime.h>

#define TILE  256
#define CIN   32
#define COUT  64
#define LSIZE 16384
#define NBITS 14

__global__ __launch_bounds__(256, 4)
void hamming_fused(const float* __restrict__ x,
                   const float* __restrict__ w_self,
                   const float* __restrict__ w_bits,
                   const float* __restrict__ mix_w,
                   const float* __restrict__ mix_b,
                   float* __restrict__ out)
{
    // LDS: x tile (overwritten with y after stage 1) + transposed mix_w
    __shared__ float xs[CIN][TILE];     // 32 KiB
    __shared__ float mws[CIN][COUT];    // 8 KiB, mws[c][o] = mix_w[o][c]

    const int tid  = threadIdx.x;       // 0..255
    const int tile = blockIdx.x;        // 0..63
    const int b    = blockIdx.y;        // 0..31
    const int base = tile * TILE;
    const float* xb = x + (size_t)b * CIN * LSIZE;

    // ---- stage mix_w (transposed) into LDS: coalesced global read ----
    #pragma unroll
    for (int i = 0; i < (CIN * COUT) / 256; ++i) {       // 8 iters
        int g = tid + i * 256;
        int o = g >> 5, c = g & 31;                      // mix_w[o][c]
        mws[c][o] = mix_w[g];
    }

    // ---- stage x tile into LDS with float4 loads ----
    #pragma unroll
    for (int i = 0; i < (CIN * TILE) / (256 * 4); ++i) { // 8 iters
        int idx = tid + i * 256;                          // row*64 + col4
        int r  = idx >> 6;
        int c4 = (idx & 63) << 2;
        *(float4*)&xs[r][c4] =
            *(const float4*)(xb + (size_t)r * LSIZE + base + c4);
    }
    __syncthreads();

    // ---- stage 1: hypercube stencil -> y (in registers) ----
    const float ws = w_self[0];
    float wb[NBITS];
    #pragma unroll
    for (int k = 0; k < NBITS; ++k) wb[k] = w_bits[k];

    const int t    = tid;          // column within tile
    const int gcol = base + t;     // global column
    float yreg[CIN];

    #pragma unroll 4
    for (int c = 0; c < CIN; ++c) {
        const float* xr = xb + (size_t)c * LSIZE;
        float a = ws * xs[c][t];
        // bits 0..7: inside the aligned 256 tile -> LDS
        #pragma unroll
        for (int k = 0; k < 8; ++k)
            a += wb[k] * xs[c][t ^ (1 << k)];
        // bits 8..13: cross-tile -> coalesced global (L2/L3-resident)
        #pragma unroll
        for (int k = 8; k < NBITS; ++k)
            a += wb[k] * xr[gcol ^ (1 << k)];
        yreg[c] = a * (1.0f / 15.0f);
    }
    __syncthreads();

    // overwrite x tile with y
    #pragma unroll
    for (int c = 0; c < CIN; ++c) xs[c][t] = yreg[c];
    __syncthreads();

    // ---- stage 2: channel mix, each thread = 4 columns x 16 outputs ----
    const int tx   = tid & 63;     // column-quad index (wave-aligned)
    const int ty   = tid >> 6;     // 0..3 -> o-range [16*ty, 16*ty+16)
    const int colb = tx << 2;
    const int o0   = ty * 16;

    float4 acc[16];
    #pragma unroll
    for (int j = 0; j < 16; ++j) {
        float bias = mix_b[o0 + j];
        acc[j] = make_float4(bias, bias, bias, bias);
    }

    #pragma unroll 4
    for (int c = 0; c < CIN; ++c) {
        float4 yv = *(float4*)&xs[c][colb];              // ds_read_b128, std pattern
        #pragma unroll
        for (int j4 = 0; j4 < 4; ++j4) {
            float4 m = *(float4*)&mws[c][o0 + j4 * 4];   // wave-uniform broadcast
            acc[j4*4+0].x += m.x * yv.x; acc[j4*4+0].y += m.x * yv.y;
            acc[j4*4+0].z += m.x * yv.z; acc[j4*4+0].w += m.x * yv.w;
            acc[j4*4+1].x += m.y * yv.x; acc[j4*4+1].y += m.y * yv.y;
            acc[j4*4+1].z += m.y * yv.z; acc[j4*4+1].w += m.y * yv.w;
            acc[j4*4+2].x += m.z * yv.x; acc[j4*4+2].y += m.z * yv.y;
            acc[j4*4+2].z += m.z * yv.z; acc[j4*4+2].w += m.z * yv.w;
            acc[j4*4+3].x += m.w * yv.x; acc[j4*4+3].y += m.w * yv.y;
            acc[j4*4+3].z += m.w * yv.z; acc[j4*4+3].w += m.w * yv.w;
        }
    }

    // ---- store: coalesced float4 ----
    float* ob = out + (size_t)b * COUT * LSIZE;
    #pragma unroll
    for (int j = 0; j < 16; ++j) {
        *(float4*)(ob + (size_t)(o0 + j) * LSIZE + base + colb) = acc[j];
    }
}

extern "C" void kernel_launch(void* const* d_in, const int* in_sizes, int n_in,
                              void* d_out, int out_size, void* d_ws, size_t ws_size,
                              hipStream_t stream) {
    const float* x      = (const float*)d_in[0];
    const float* w_self = (const float*)d_in[1];
    const float* w_bits = (const float*)d_in[2];
    const float* mix_w  = (const float*)d_in[3];
    const float* mix_b  = (const float*)d_in[4];
    float* out = (float*)d_out;

    dim3 grid(LSIZE / TILE, 32);   // 64 tiles x 32 batches = 2048 blocks
    hamming_fused<<<grid, 256, 0, stream>>>(x, w_self, w_bits, mix_w, mix_b, out);
}

// Round 3
// 210.516 us; speedup vs baseline: 1.0697x; 1.0697x over previous
//
#include <hip/hip_runtime.h>

#define TILE  256
#define CIN   32
#define COUT  64
#define LSIZE 16384
#define NBITS 14

typedef float vfloat4 __attribute__((ext_vector_type(4)));

__global__ __launch_bounds__(256, 4)
void hamming_fused(const float* __restrict__ x,
                   const float* __restrict__ w_self,
                   const float* __restrict__ w_bits,
                   const float* __restrict__ mix_w,
                   const float* __restrict__ mix_b,
                   float* __restrict__ out)
{
    __shared__ float xs[CIN][TILE];     // 32 KiB (x tile, overwritten with y)
    __shared__ float mws[CIN][COUT];    // 8 KiB, mws[c][o] = mix_w[o][c]

    const int tid = threadIdx.x;        // 0..255

    // ---- XCD-aware remap: consecutive dispatch ids round-robin across the 8
    // XCDs, so give each XCD 4 whole batches (x[b] slab = 2 MiB fits its 4 MiB
    // L2). All 64 tiles of a batch then share one L2 -> cross-tile taps hit L2.
    const int d    = blockIdx.x;        // 0..2047
    const int xcd  = d & 7;
    const int j    = d >> 3;            // 0..255 per-XCD sequence
    const int b    = xcd * 4 + (j >> 6);// 0..31
    const int tile = j & 63;            // 0..63
    const int base = tile * TILE;
    const float* xb = x + (size_t)b * CIN * LSIZE;

    // ---- stage mix_w (transposed) into LDS ----
    #pragma unroll
    for (int i = 0; i < (CIN * COUT) / 256; ++i) {       // 8 iters
        int g = tid + i * 256;
        int o = g >> 5, c = g & 31;                      // mix_w[o][c]
        mws[c][o] = mix_w[g];
    }

    // ---- stage x tile into LDS with float4 loads ----
    #pragma unroll
    for (int i = 0; i < (CIN * TILE) / (256 * 4); ++i) { // 8 iters
        int idx = tid + i * 256;
        int r  = idx >> 6;
        int c4 = (idx & 63) << 2;
        *(float4*)&xs[r][c4] =
            *(const float4*)(xb + (size_t)r * LSIZE + base + c4);
    }
    __syncthreads();

    // ---- stage 1: hypercube stencil -> y (in registers) ----
    const float ws = w_self[0];
    float wb[NBITS];
    #pragma unroll
    for (int k = 0; k < NBITS; ++k) wb[k] = w_bits[k];

    const int t    = tid;
    const int gcol = base + t;
    float yreg[CIN];

    // chunk channels by 8: issue 48 cross-tile loads (coalesced, L2-resident
    // after the XCD remap) before consuming -> high MLP
    #pragma unroll
    for (int c0 = 0; c0 < CIN; c0 += 8) {
        float pf[8][6];
        #pragma unroll
        for (int cc = 0; cc < 8; ++cc) {
            const float* xr = xb + (size_t)(c0 + cc) * LSIZE;
            #pragma unroll
            for (int k = 0; k < 6; ++k)
                pf[cc][k] = xr[gcol ^ (TILE << k)];      // bits 8..13
        }
        #pragma unroll
        for (int cc = 0; cc < 8; ++cc) {
            int c = c0 + cc;
            float a = ws * xs[c][t];
            #pragma unroll
            for (int k = 0; k < 8; ++k)                  // bits 0..7: in-tile
                a += wb[k] * xs[c][t ^ (1 << k)];
            #pragma unroll
            for (int k = 0; k < 6; ++k)
                a += wb[8 + k] * pf[cc][k];
            yreg[c] = a * (1.0f / 15.0f);
        }
    }
    __syncthreads();

    #pragma unroll
    for (int c = 0; c < CIN; ++c) xs[c][t] = yreg[c];
    __syncthreads();

    // ---- stage 2: channel mix, each thread = 4 columns x 16 outputs ----
    const int tx   = tid & 63;
    const int ty   = tid >> 6;
    const int colb = tx << 2;
    const int o0   = ty * 16;

    float4 acc[16];
    #pragma unroll
    for (int jj = 0; jj < 16; ++jj) {
        float bias = mix_b[o0 + jj];
        acc[jj] = make_float4(bias, bias, bias, bias);
    }

    #pragma unroll 4
    for (int c = 0; c < CIN; ++c) {
        float4 yv = *(float4*)&xs[c][colb];
        #pragma unroll
        for (int j4 = 0; j4 < 4; ++j4) {
            float4 m = *(float4*)&mws[c][o0 + j4 * 4];   // wave-uniform
            acc[j4*4+0].x += m.x * yv.x; acc[j4*4+0].y += m.x * yv.y;
            acc[j4*4+0].z += m.x * yv.z; acc[j4*4+0].w += m.x * yv.w;
            acc[j4*4+1].x += m.y * yv.x; acc[j4*4+1].y += m.y * yv.y;
            acc[j4*4+1].z += m.y * yv.z; acc[j4*4+1].w += m.y * yv.w;
            acc[j4*4+2].x += m.z * yv.x; acc[j4*4+2].y += m.z * yv.y;
            acc[j4*4+2].z += m.z * yv.z; acc[j4*4+2].w += m.z * yv.w;
            acc[j4*4+3].x += m.w * yv.x; acc[j4*4+3].y += m.w * yv.y;
            acc[j4*4+3].z += m.w * yv.z; acc[j4*4+3].w += m.w * yv.w;
        }
    }

    // ---- store: coalesced float4, NON-TEMPORAL (don't evict x from L2/LLC) ----
    float* ob = out + (size_t)b * COUT * LSIZE;
    #pragma unroll
    for (int jj = 0; jj < 16; ++jj) {
        vfloat4 v; v.x = acc[jj].x; v.y = acc[jj].y; v.z = acc[jj].z; v.w = acc[jj].w;
        vfloat4* p = (vfloat4*)(ob + (size_t)(o0 + jj) * LSIZE + base + colb);
        __builtin_nontemporal_store(v, p);
    }
}

extern "C" void kernel_launch(void* const* d_in, const int* in_sizes, int n_in,
                              void* d_out, int out_size, void* d_ws, size_t ws_size,
                              hipStream_t stream) {
    const float* x      = (const float*)d_in[0];
    const float* w_self = (const float*)d_in[1];
    const float* w_bits = (const float*)d_in[2];
    const float* mix_w  = (const float*)d_in[3];
    const float* mix_b  = (const float*)d_in[4];
    float* out = (float*)d_out;

    hamming_fused<<<dim3(2048), 256, 0, stream>>>(x, w_self, w_bits, mix_w, mix_b, out);
}